// Round 8
// baseline (325.795 us; speedup 1.0000x reference)
//
#include <hip/hip_runtime.h>
#include <hip/hip_bf16.h>

#define NQ     14
#define DIM    16384
#define NLAYER 16
#define BATCH  512
#define NT     1024

typedef float v2f __attribute__((ext_vector_type(2)));

// bijective LDS swizzle (XOR bits 5..9 into 0..4), in BYTE units (float2=8B).
// XOR-linear: POSB(a^b) = POSB(a)^POSB(b)
__device__ __forceinline__ constexpr int POSB(int x){ return (x ^ ((x >> 5) & 31)) << 3; }

__device__ __forceinline__ float bf2f(unsigned int u16){
  union { unsigned int i; float f; } v; v.i = u16 << 16; return v.f;
}

__device__ __forceinline__ float thv(const void* th, int i, bool b16){
  return b16 ? bf2f(((const unsigned short*)th)[i]) : ((const float*)th)[i];
}

// Composed CNOT-ring source map (GF(2)-linear): psi_out[x] = psi_in[srcF(x)]
__device__ int srcF(int x){
  int v = x;
  #pragma unroll
  for (int k = 13; k >= 0; --k){
    int tb = 13 - ((k + 1) % 14);
    v ^= ((v >> (13 - k)) & 1) << tb;
  }
  return v;
}

// complex multiply: packed v_pk_mul + v_pk_fma
__device__ __forceinline__ v2f cmul(v2f a, v2f b){
  v2f as = a.yx;
  v2f br = (v2f){ b.x,  b.x};
  v2f bi = (v2f){-b.y,  b.y};
  return a * br + as * bi;
}

// RY rotation on a pair: 4 packed instrs
__device__ __forceinline__ void rot2(v2f& a0, v2f& a1, float c, float s){
  v2f c2 = (v2f){c, c}, s2 = (v2f){s, s};
  v2f t0 = a0;
  a0 = a0 * c2 - a1 * s2;
  a1 = t0 * s2 + a1 * c2;
}

// 4-pass ladder (14 qubits, >=4 passes at 16 amps/thread -> minimum):
//   P1: gather(CNOT^-1) + RZ0 + RY q0-3   (x bits 13..10, j=reg)  g[16]
//   P2: RY q4-7                           (x bits  9..6)          h[16]
//   P3: RY q8-10                          (x bits  5..3)          h[8] x2
//   P4: RY q11-13 + RZ2                   (x bits  2..0)          h[8] x2
// Each map: bank-pair bits (x0^x5,x1^x6,x2^x7,x3^x8) rank-4 over lane bits
// -> uniform 4 lanes/bank-pair = wave64 b64 floor.
__global__ __launch_bounds__(NT) __attribute__((amdgpu_waves_per_eu(4, 4)))
void qnn_circuit(const void* __restrict__ zraw,
                 const void* __restrict__ theta,
                 float* __restrict__ out)
{
  __shared__ v2f   S[DIM];
  __shared__ v2f   ph0H[128], ph0L[128], ph2H[128], ph2L[128];
  __shared__ float csT[28];
  __shared__ int   sHB[128], sLB[128];   // pre-swizzled BYTE offsets of srcF
  __shared__ float red[16*5];

  char* Sb = (char*)S;
  const int t = threadIdx.x;
  const int b = blockIdx.x;

  // ---- sniff theta dtype: bf16 vs float32 ----
  int pred = 0;
  if (t < 336){
    unsigned int w  = ((const unsigned int*)theta)[t];
    unsigned int lo = w & 0xffffu;
    unsigned int e  = (lo >> 7) & 0xffu;
    pred = (e >= 100 && e <= 140) || (lo == 0);
  }
  const bool th_b16 = (__syncthreads_count(pred) > 250);

  // ---- sniff z format: bf16 (re,im) pairs vs float32 real-only ----
  pred = 0;
  if (t < 256){
    unsigned int w  = ((const unsigned int*)zraw)[t];
    unsigned int lo = w & 0xffffu;
    unsigned int e  = (lo >> 7) & 0xffu;
    pred = (e >= 88 && e <= 140) || (lo == 0);
  }
  const bool z_b16 = (__syncthreads_count(pred) > 160);

  if (t < 128){ sHB[t] = POSB(srcF(t << 7)); sLB[t] = POSB(srcF(t)); }

  // ---- load z -> LDS (swizzled) ----
  if (z_b16){
    const uint4* zb = (const uint4*)((const unsigned short*)zraw + (size_t)b * (DIM * 2));
    #pragma unroll 1
    for (int jj = 0; jj < 4; ++jj){
      int x4 = t + NT * jj;
      uint4 w = zb[x4];
      int xb = x4 * 4;
      *(v2f*)(Sb + POSB(xb+0)) = (v2f){bf2f(w.x & 0xffffu), bf2f(w.x >> 16)};
      *(v2f*)(Sb + POSB(xb+1)) = (v2f){bf2f(w.y & 0xffffu), bf2f(w.y >> 16)};
      *(v2f*)(Sb + POSB(xb+2)) = (v2f){bf2f(w.z & 0xffffu), bf2f(w.z >> 16)};
      *(v2f*)(Sb + POSB(xb+3)) = (v2f){bf2f(w.w & 0xffffu), bf2f(w.w >> 16)};
    }
  } else {
    const float4* zf = (const float4*)((const float*)zraw + (size_t)b * DIM);
    #pragma unroll 1
    for (int jj = 0; jj < 4; ++jj){
      int x4 = t + NT * jj;
      float4 w = zf[x4];
      int xb = x4 * 4;
      *(v2f*)(Sb + POSB(xb+0)) = (v2f){w.x, 0.f};
      *(v2f*)(Sb + POSB(xb+1)) = (v2f){w.y, 0.f};
      *(v2f*)(Sb + POSB(xb+2)) = (v2f){w.z, 0.f};
      *(v2f*)(Sb + POSB(xb+3)) = (v2f){w.w, 0.f};
    }
  }
  __syncthreads();

  const int pwb = POSB(t);        // P1 base (bits of t < 10 -> swizzle-closed)
  const int hb  = t >> 7;         // P1 hi-table base index
  const int slB = sLB[t & 127];   // visible after the sync above

  // P2 base: x = (t&63) | (j<<6) | ((t>>6)<<10)
  const int pb2 = POSB(((t >> 6) << 10) | (t & 63));
  // P3 base (per it): x = (t&7) | ((t>>3)&7)<<6 | ((t>>6)&15)<<9 | it<<13
  const int pb3 = POSB((t & 7) | (((t >> 3) & 7) << 6) | (((t >> 6) & 15) << 9));
  // P4 base (per it): x5..7 = t0..2, x3 = t3, x8 = t4, x4 = t5, x9..12 = t6..9, x13 = it
  const int x4base = ((t & 7) << 5) | (((t >> 3) & 1) << 3) | (((t >> 4) & 1) << 8)
                   | (((t >> 5) & 1) << 4) | (((t >> 6) & 15) << 9);
  const int pb4 = POSB(x4base);

  for (int l = 0; l < NLAYER; ++l){
    const int thb = l * 42;

    // ---- prep RZ phase tables + RY angles (overlaps P1 gather) ----
    if (t < 512){
      int grp = t >> 7, idx = t & 127;
      int tz = thb + ((grp >= 2) ? 28 : 0);
      float ph = 0.f;
      if ((grp & 1) == 0){
        #pragma unroll
        for (int w = 0; w < 7; ++w)
          ph += (((idx >> (6 - w)) & 1) ? 0.5f : -0.5f) * thv(theta, tz + w, th_b16);
      } else {
        #pragma unroll
        for (int w = 7; w < 14; ++w)
          ph += (((idx >> (13 - w)) & 1) ? 0.5f : -0.5f) * thv(theta, tz + w, th_b16);
      }
      float sn, cs; sincosf(ph, &sn, &cs);
      v2f v = (v2f){cs, sn};
      if      (grp == 0) ph0H[idx] = v;
      else if (grp == 1) ph0L[idx] = v;
      else if (grp == 2) ph2H[idx] = v;
      else               ph2L[idx] = v;
    } else if (t < 512 + 14){
      int q = t - 512;
      float sn, cs; sincosf(0.5f * thv(theta, thb + 14 + q, th_b16), &sn, &cs);
      csT[2*q] = cs; csT[2*q+1] = sn;
    }

    // ---- P1: gather + RZ0 + RY q0-3 (x = t | (j<<10)) ----
    {
      v2f g[16];
      if (l == 0){
        #pragma unroll
        for (int j = 0; j < 16; ++j) g[j] = *(v2f*)(Sb + (pwb ^ (j << 13)));
      } else {
        #pragma unroll
        for (int j = 0; j < 16; ++j)
          g[j] = *(v2f*)(Sb + (sHB[hb + 8*j] ^ slB));
      }
      __syncthreads();   // gathers done; this layer's tables visible

      {
        v2f cl = ph0L[t & 127];
        #pragma unroll
        for (int j = 0; j < 16; ++j)
          g[j] = cmul(g[j], cmul(ph0H[hb + 8*j], cl));
      }
      #pragma unroll
      for (int q = 0; q < 4; ++q){
        float c = csT[2*q], sn = csT[2*q+1];
        int m = 8 >> q;
        #pragma unroll
        for (int j = 0; j < 16; ++j){
          if (j & m) continue;
          rot2(g[j], g[j | m], c, sn);
        }
      }
      #pragma unroll
      for (int j = 0; j < 16; ++j) *(v2f*)(Sb + (pwb ^ (j << 13))) = g[j];
    }
    __syncthreads();

    // ---- P2: RY q4-7 (x bits 9..6; q4<->j3 ... q7<->j0) ----
    {
      v2f h[16];
      #pragma unroll
      for (int j = 0; j < 16; ++j)
        h[j] = *(v2f*)(Sb + (pb2 ^ (((j << 6) | ((j << 1) & 31)) << 3)));
      #pragma unroll
      for (int q = 0; q < 4; ++q){
        float c = csT[2*(4+q)], sn = csT[2*(4+q)+1];
        int m = 8 >> q;
        #pragma unroll
        for (int j = 0; j < 16; ++j){
          if (j & m) continue;
          rot2(h[j], h[j | m], c, sn);
        }
      }
      #pragma unroll
      for (int j = 0; j < 16; ++j)
        *(v2f*)(Sb + (pb2 ^ (((j << 6) | ((j << 1) & 31)) << 3))) = h[j];
    }
    __syncthreads();

    // ---- P3: RY q8-10 (x bits 5..3; q8<->j2, q9<->j1, q10<->j0) ----
    #pragma unroll
    for (int it = 0; it < 2; ++it){
      int pb = pb3 ^ (it << 16);            // POSB(it<<13) = it<<16
      v2f h[8];
      #pragma unroll
      for (int j = 0; j < 8; ++j)
        h[j] = *(v2f*)(Sb + (pb ^ (((j << 3) | (j >> 2)) << 3)));
      #pragma unroll
      for (int q = 0; q < 3; ++q){
        float c = csT[2*(8+q)], sn = csT[2*(8+q)+1];
        int m = 4 >> q;
        #pragma unroll
        for (int j = 0; j < 8; ++j){
          if (j & m) continue;
          rot2(h[j], h[j | m], c, sn);
        }
      }
      #pragma unroll
      for (int j = 0; j < 8; ++j)
        *(v2f*)(Sb + (pb ^ (((j << 3) | (j >> 2)) << 3))) = h[j];
    }
    __syncthreads();

    // ---- P4: RY q11-13 (x bits 2..0) + RZ2 ----
    #pragma unroll
    for (int it = 0; it < 2; ++it){
      int pb = pb4 ^ (it << 16);
      v2f h[8];
      #pragma unroll
      for (int j = 0; j < 8; ++j) h[j] = *(v2f*)(Sb + (pb ^ (j << 3)));
      #pragma unroll
      for (int q = 0; q < 3; ++q){
        float c = csT[2*(11+q)], sn = csT[2*(11+q)+1];
        int m = 4 >> q;
        #pragma unroll
        for (int j = 0; j < 8; ++j){
          if (j & m) continue;
          rot2(h[j], h[j | m], c, sn);
        }
      }
      {
        int x0 = x4base | (it << 13);
        v2f chh = ph2H[x0 >> 7];
        int lbase = x0 & 127;
        #pragma unroll
        for (int j = 0; j < 8; ++j)
          h[j] = cmul(h[j], cmul(chh, ph2L[lbase | j]));
      }
      #pragma unroll
      for (int j = 0; j < 8; ++j) *(v2f*)(Sb + (pb ^ (j << 3))) = h[j];
    }
    __syncthreads();
  }

  // ---- measurement (final CNOT ring pending -> gather via src tables) ----
  float z0=0.f, z1=0.f, x0s=0.f, x1s=0.f, y0s=0.f;
  {
    v2f g[16];
    #pragma unroll
    for (int j = 0; j < 16; ++j)
      g[j] = *(v2f*)(Sb + (sHB[hb + 8*j] ^ slB));

    #pragma unroll
    for (int j = 0; j < 16; ++j){
      float pw = g[j].x*g[j].x + g[j].y*g[j].y;
      z0 += (j & 8) ? -pw : pw;     // qubit0 = x bit13 = j bit3
      z1 += (j & 4) ? -pw : pw;     // qubit1 = x bit12 = j bit2
    }
    #pragma unroll
    for (int j = 0; j < 8; ++j){
      v2f p0 = g[j], p1 = g[j+8];
      x0s += 2.f*(p0.x*p1.x + p0.y*p1.y);
      y0s += 2.f*(p0.x*p1.y - p0.y*p1.x);
    }
    #pragma unroll
    for (int j = 0; j < 16; ++j){
      if (j & 4) continue;
      v2f p0 = g[j], p1 = g[j|4];
      x1s += 2.f*(p0.x*p1.x + p0.y*p1.y);
    }
  }
  #pragma unroll
  for (int o = 32; o >= 1; o >>= 1){
    z0  += __shfl_down(z0,  o, 64);
    z1  += __shfl_down(z1,  o, 64);
    x0s += __shfl_down(x0s, o, 64);
    x1s += __shfl_down(x1s, o, 64);
    y0s += __shfl_down(y0s, o, 64);
  }
  int wid = t >> 6, lane = t & 63;
  if (lane == 0){
    red[wid*5+0]=z0; red[wid*5+1]=z1; red[wid*5+2]=x0s; red[wid*5+3]=x1s; red[wid*5+4]=y0s;
  }
  __syncthreads();
  if (t < 5){
    float sum = 0.f;
    #pragma unroll
    for (int w = 0; w < 16; ++w) sum += red[w*5 + t];
    out[1 + b*5 + t] = sum;
  }
}

__global__ __launch_bounds__(512)
void qnn_loss(const int* __restrict__ y, float* __restrict__ out)
{
  __shared__ float red[8];
  int t = threadIdx.x;
  const float* o = out + 1 + t*5;
  float o0=o[0], o1=o[1], o2=o[2], o3=o[3], o4=o[4];
  float m = fmaxf(fmaxf(fmaxf(o0,o1), fmaxf(o2,o3)), o4);
  float sum = expf(o0-m)+expf(o1-m)+expf(o2-m)+expf(o3-m)+expf(o4-m);
  float lse = m + logf(sum);
  int yi = y[t]; yi = yi < 0 ? 0 : (yi > 4 ? 4 : yi);
  float lb = lse - o[yi];

  #pragma unroll
  for (int ofs = 32; ofs >= 1; ofs >>= 1) lb += __shfl_down(lb, ofs, 64);
  if ((t & 63) == 0) red[t >> 6] = lb;
  __syncthreads();
  if (t == 0){
    float s = 0.f;
    #pragma unroll
    for (int w = 0; w < 8; ++w) s += red[w];
    out[0] = s / (float)BATCH;
  }
}

extern "C" void kernel_launch(void* const* d_in, const int* in_sizes, int n_in,
                              void* d_out, int out_size, void* d_ws, size_t ws_size,
                              hipStream_t stream)
{
  const void* z     = d_in[0];
  const void* theta = d_in[1];
  const int*  y     = (const int*)d_in[2];
  float*      out   = (float*)d_out;

  qnn_circuit<<<BATCH, NT, 0, stream>>>(z, theta, out);
  qnn_loss<<<1, 512, 0, stream>>>(y, out);
}

// Round 9
// 305.105 us; speedup vs baseline: 1.0678x; 1.0678x over previous
//
#include <hip/hip_runtime.h>
#include <hip/hip_bf16.h>

#define NQ     14
#define DIM    16384
#define NLAYER 16
#define BATCH  512
#define NT     1024

typedef float v2f __attribute__((ext_vector_type(2)));

// bijective LDS swizzle (XOR bits 5..9 into 0..4), BYTE units (float2=8B).
// XOR-linear: POSB(a^b) = POSB(a)^POSB(b)
__device__ __forceinline__ constexpr int POSB(int x){ return (x ^ ((x >> 5) & 31)) << 3; }

__device__ __forceinline__ float bf2f(unsigned int u16){
  union { unsigned int i; float f; } v; v.i = u16 << 16; return v.f;
}

__device__ __forceinline__ float thv(const void* th, int i, bool b16){
  return b16 ? bf2f(((const unsigned short*)th)[i]) : ((const float*)th)[i];
}

// Composed CNOT-ring source map (GF(2)-linear): psi_out[x] = psi_in[srcF(x)]
__device__ int srcF(int x){
  int v = x;
  #pragma unroll
  for (int k = 13; k >= 0; --k){
    int tb = 13 - ((k + 1) % 14);
    v ^= ((v >> (13 - k)) & 1) << tb;
  }
  return v;
}

// complex multiply in 2 VOP3P instructions:
//   t  = a * b.xx                        (op_sel_hi src1 -> lo half)
//   d.lo = -a.y*b.y + t.lo ; d.hi = a.x*b.y + t.hi
__device__ __forceinline__ v2f cmul(v2f a, v2f b){
  v2f t, d;
  asm("v_pk_mul_f32 %0, %1, %2 op_sel:[0,0] op_sel_hi:[1,0]"
      : "=v"(t) : "v"(a), "v"(b));
  asm("v_pk_fma_f32 %0, %1, %2, %3 op_sel:[1,1,0] op_sel_hi:[0,1,1] neg_lo:[0,1,0]"
      : "=v"(d) : "v"(a), "v"(b), "v"(t));
  return d;
}

// RY rotation on a pair: 4 packed instrs (2 pk_mul + 2 pk_fma)
__device__ __forceinline__ void rot2(v2f& a0, v2f& a1, float c, float s){
  v2f c2 = (v2f){c, c}, s2 = (v2f){s, s};
  v2f t0 = a0;
  a0 = a0 * c2 - a1 * s2;
  a1 = t0 * s2 + a1 * c2;
}

// r7 5-pass ladder (all maps rank-4 per 32-lane HALF-wave -> b64 conflict floor):
//   P1 : gather(CNOT^-1) + RZ0 + RY q0-3  (x bits 13..10)  g[16]
//   P2': RY q4-6  (x bits 9..7)                            h[8] x2
//   P3': RY q7-9  (x bits 6..4)                            h[8] x2
//   P4': RY q10-11 (x bits 3..2)                           h[4] x4
//   P5': RY q12-13 (x bits 1..0) + RZ2                     h[4] x4
__global__ __launch_bounds__(NT) __attribute__((amdgpu_waves_per_eu(4, 4)))
void qnn_circuit(const void* __restrict__ zraw,
                 const void* __restrict__ theta,
                 float* __restrict__ out)
{
  __shared__ v2f   S[DIM];
  __shared__ v2f   ph0H[128], ph0L[128], ph2H[128], ph2L[128];
  __shared__ float csT[28];
  __shared__ int   sHB[128], sLB[128];   // pre-swizzled BYTE offsets of srcF
  __shared__ float red[16*5];

  char* Sb = (char*)S;
  const int t = threadIdx.x;
  const int b = blockIdx.x;

  // ---- sniff theta dtype: bf16 vs float32 ----
  int pred = 0;
  if (t < 336){
    unsigned int w  = ((const unsigned int*)theta)[t];
    unsigned int lo = w & 0xffffu;
    unsigned int e  = (lo >> 7) & 0xffu;
    pred = (e >= 100 && e <= 140) || (lo == 0);
  }
  const bool th_b16 = (__syncthreads_count(pred) > 250);

  // ---- sniff z format: bf16 (re,im) pairs vs float32 real-only ----
  pred = 0;
  if (t < 256){
    unsigned int w  = ((const unsigned int*)zraw)[t];
    unsigned int lo = w & 0xffffu;
    unsigned int e  = (lo >> 7) & 0xffu;
    pred = (e >= 88 && e <= 140) || (lo == 0);
  }
  const bool z_b16 = (__syncthreads_count(pred) > 160);

  if (t < 128){ sHB[t] = POSB(srcF(t << 7)); sLB[t] = POSB(srcF(t)); }

  // ---- load z -> LDS (swizzled) ----
  if (z_b16){
    const uint4* zb = (const uint4*)((const unsigned short*)zraw + (size_t)b * (DIM * 2));
    #pragma unroll 1
    for (int jj = 0; jj < 4; ++jj){
      int x4 = t + NT * jj;
      uint4 w = zb[x4];
      int xb = x4 * 4;
      *(v2f*)(Sb + POSB(xb+0)) = (v2f){bf2f(w.x & 0xffffu), bf2f(w.x >> 16)};
      *(v2f*)(Sb + POSB(xb+1)) = (v2f){bf2f(w.y & 0xffffu), bf2f(w.y >> 16)};
      *(v2f*)(Sb + POSB(xb+2)) = (v2f){bf2f(w.z & 0xffffu), bf2f(w.z >> 16)};
      *(v2f*)(Sb + POSB(xb+3)) = (v2f){bf2f(w.w & 0xffffu), bf2f(w.w >> 16)};
    }
  } else {
    const float4* zf = (const float4*)((const float*)zraw + (size_t)b * DIM);
    #pragma unroll 1
    for (int jj = 0; jj < 4; ++jj){
      int x4 = t + NT * jj;
      float4 w = zf[x4];
      int xb = x4 * 4;
      *(v2f*)(Sb + POSB(xb+0)) = (v2f){w.x, 0.f};
      *(v2f*)(Sb + POSB(xb+1)) = (v2f){w.y, 0.f};
      *(v2f*)(Sb + POSB(xb+2)) = (v2f){w.z, 0.f};
      *(v2f*)(Sb + POSB(xb+3)) = (v2f){w.w, 0.f};
    }
  }
  __syncthreads();

  const int pwb = POSB(t);        // P1 base
  const int hb  = t >> 7;         // P1 hi-table base index
  const int slB = sLB[t & 127];   // visible after the sync above

  // Pass bases hoisted out of the layer loop; per-it delta is an XOR
  // (s = t | (it<<10) is carry-free into each field).
  const int pb2 = POSB(((t >> 7) << 10) | (t & 127));                       // it -> ^ (it<<16)
  const int pb3 = POSB(((t >> 7) << 10) | (((t >> 5) & 1) << 9)
                     | (((t >> 4) & 1) << 8) | (((t >> 6) & 1) << 7) | (t & 15)); // ^ (it<<16)
  const int pb4 = POSB(((t >> 8) << 10) | (((t >> 4) & 1) << 9) | (((t >> 3) & 1) << 8)
                     | (((t >> 2) & 1) << 7) | (((t >> 6) & 1) << 6) | (((t >> 5) & 1) << 5)
                     | (((t >> 7) & 1) << 4) | (t & 3));                    // ^ (it<<15)
  const int x5base = ((t >> 8) << 10) | ((t & 31) << 5) | (((t >> 7) & 1) << 4)
                   | (((t >> 6) & 1) << 3) | (((t >> 5) & 1) << 2);
  const int pb5 = POSB(x5base);                                             // ^ (it<<15)
  const int lb5 = x5base & 127;   // ph2L index base (it doesn't touch low 7)

  for (int l = 0; l < NLAYER; ++l){
    const int thb = l * 42;

    // ---- prep RZ phase tables + RY angles (overlaps P1 gather) ----
    if (t < 512){
      int grp = t >> 7, idx = t & 127;
      int tz = thb + ((grp >= 2) ? 28 : 0);
      float ph = 0.f;
      if ((grp & 1) == 0){
        #pragma unroll
        for (int w = 0; w < 7; ++w)
          ph += (((idx >> (6 - w)) & 1) ? 0.5f : -0.5f) * thv(theta, tz + w, th_b16);
      } else {
        #pragma unroll
        for (int w = 7; w < 14; ++w)
          ph += (((idx >> (13 - w)) & 1) ? 0.5f : -0.5f) * thv(theta, tz + w, th_b16);
      }
      float sn, cs; sincosf(ph, &sn, &cs);
      v2f v = (v2f){cs, sn};
      if      (grp == 0) ph0H[idx] = v;
      else if (grp == 1) ph0L[idx] = v;
      else if (grp == 2) ph2H[idx] = v;
      else               ph2L[idx] = v;
    } else if (t < 512 + 14){
      int q = t - 512;
      float sn, cs; sincosf(0.5f * thv(theta, thb + 14 + q, th_b16), &sn, &cs);
      csT[2*q] = cs; csT[2*q+1] = sn;
    }

    // ---- P1: gather + RZ0 + RY q0-3 (x = t | (j<<10)) ----
    {
      v2f g[16];
      if (l == 0){
        #pragma unroll
        for (int j = 0; j < 16; ++j) g[j] = *(v2f*)(Sb + (pwb ^ (j << 13)));
      } else {
        #pragma unroll
        for (int j = 0; j < 16; ++j)
          g[j] = *(v2f*)(Sb + (sHB[hb + 8*j] ^ slB));
      }
      __syncthreads();   // gathers done; this layer's tables visible

      {
        v2f cl = ph0L[t & 127];
        #pragma unroll
        for (int j = 0; j < 16; ++j)
          g[j] = cmul(g[j], cmul(ph0H[hb + 8*j], cl));
      }
      #pragma unroll
      for (int q = 0; q < 4; ++q){
        float c = csT[2*q], sn = csT[2*q+1];
        int m = 8 >> q;
        #pragma unroll
        for (int j = 0; j < 16; ++j){
          if (j & m) continue;
          rot2(g[j], g[j | m], c, sn);
        }
      }
      #pragma unroll
      for (int j = 0; j < 16; ++j) *(v2f*)(Sb + (pwb ^ (j << 13))) = g[j];
    }
    __syncthreads();

    // ---- P2': RY q4-6 (x bits 9..7); offset POSB(j<<7) = ((j<<7)|(j<<2))<<3 ----
    #pragma unroll 1
    for (int it = 0; it < 2; ++it){
      int pb = pb2 ^ (it << 16);
      v2f h[8];
      #pragma unroll
      for (int j = 0; j < 8; ++j) h[j] = *(v2f*)(Sb + (pb ^ (((j << 7) | (j << 2)) << 3)));
      #pragma unroll
      for (int q = 0; q < 3; ++q){
        float c = csT[2*(4+q)], sn = csT[2*(4+q)+1];
        int m = 4 >> q;
        #pragma unroll
        for (int j = 0; j < 8; ++j){
          if (j & m) continue;
          rot2(h[j], h[j | m], c, sn);
        }
      }
      #pragma unroll
      for (int j = 0; j < 8; ++j) *(v2f*)(Sb + (pb ^ (((j << 7) | (j << 2)) << 3))) = h[j];
    }
    __syncthreads();

    // ---- P3': RY q7-9 (x bits 6..4); offset POSB(j<<4) = ((j<<4)|(j>>1))<<3 ----
    #pragma unroll 1
    for (int it = 0; it < 2; ++it){
      int pb = pb3 ^ (it << 16);
      v2f h[8];
      #pragma unroll
      for (int j = 0; j < 8; ++j) h[j] = *(v2f*)(Sb + (pb ^ (((j << 4) | (j >> 1)) << 3)));
      #pragma unroll
      for (int q = 0; q < 3; ++q){
        float c = csT[2*(7+q)], sn = csT[2*(7+q)+1];
        int m = 4 >> q;
        #pragma unroll
        for (int j = 0; j < 8; ++j){
          if (j & m) continue;
          rot2(h[j], h[j | m], c, sn);
        }
      }
      #pragma unroll
      for (int j = 0; j < 8; ++j) *(v2f*)(Sb + (pb ^ (((j << 4) | (j >> 1)) << 3))) = h[j];
    }
    __syncthreads();

    // ---- P4': RY q10-11 (x bits 3..2); offset POSB(j<<2) = j<<5 ----
    #pragma unroll 1
    for (int it = 0; it < 4; ++it){
      int pb = pb4 ^ (it << 15);
      v2f h[4];
      #pragma unroll
      for (int j = 0; j < 4; ++j) h[j] = *(v2f*)(Sb + (pb ^ (j << 5)));
      #pragma unroll
      for (int q = 0; q < 2; ++q){
        float c = csT[2*(10+q)], sn = csT[2*(10+q)+1];
        int m = 2 >> q;
        #pragma unroll
        for (int j = 0; j < 4; ++j){
          if (j & m) continue;
          rot2(h[j], h[j | m], c, sn);
        }
      }
      #pragma unroll
      for (int j = 0; j < 4; ++j) *(v2f*)(Sb + (pb ^ (j << 5))) = h[j];
    }
    __syncthreads();

    // ---- P5': RY q12-13 (x bits 1..0) + RZ2; offset POSB(j) = j<<3 ----
    #pragma unroll 1
    for (int it = 0; it < 4; ++it){
      int pb = pb5 ^ (it << 15);
      v2f h[4];
      #pragma unroll
      for (int j = 0; j < 4; ++j) h[j] = *(v2f*)(Sb + (pb ^ (j << 3)));
      #pragma unroll
      for (int q = 0; q < 2; ++q){
        float c = csT[2*(12+q)], sn = csT[2*(12+q)+1];
        int m = 2 >> q;
        #pragma unroll
        for (int j = 0; j < 4; ++j){
          if (j & m) continue;
          rot2(h[j], h[j | m], c, sn);
        }
      }
      {
        v2f chh = ph2H[(x5base >> 7) | (it << 5)];
        #pragma unroll
        for (int j = 0; j < 4; ++j)
          h[j] = cmul(h[j], cmul(chh, ph2L[lb5 | j]));
      }
      #pragma unroll
      for (int j = 0; j < 4; ++j) *(v2f*)(Sb + (pb ^ (j << 3))) = h[j];
    }
    __syncthreads();
  }

  // ---- measurement (final CNOT ring pending -> gather via src tables) ----
  float z0=0.f, z1=0.f, x0s=0.f, x1s=0.f, y0s=0.f;
  {
    v2f g[16];
    #pragma unroll
    for (int j = 0; j < 16; ++j)
      g[j] = *(v2f*)(Sb + (sHB[hb + 8*j] ^ slB));

    #pragma unroll
    for (int j = 0; j < 16; ++j){
      float pw = g[j].x*g[j].x + g[j].y*g[j].y;
      z0 += (j & 8) ? -pw : pw;     // qubit0 = x bit13 = j bit3
      z1 += (j & 4) ? -pw : pw;     // qubit1 = x bit12 = j bit2
    }
    #pragma unroll
    for (int j = 0; j < 8; ++j){
      v2f p0 = g[j], p1 = g[j+8];
      x0s += 2.f*(p0.x*p1.x + p0.y*p1.y);
      y0s += 2.f*(p0.x*p1.y - p0.y*p1.x);
    }
    #pragma unroll
    for (int j = 0; j < 16; ++j){
      if (j & 4) continue;
      v2f p0 = g[j], p1 = g[j|4];
      x1s += 2.f*(p0.x*p1.x + p0.y*p1.y);
    }
  }
  #pragma unroll
  for (int o = 32; o >= 1; o >>= 1){
    z0  += __shfl_down(z0,  o, 64);
    z1  += __shfl_down(z1,  o, 64);
    x0s += __shfl_down(x0s, o, 64);
    x1s += __shfl_down(x1s, o, 64);
    y0s += __shfl_down(y0s, o, 64);
  }
  int wid = t >> 6, lane = t & 63;
  if (lane == 0){
    red[wid*5+0]=z0; red[wid*5+1]=z1; red[wid*5+2]=x0s; red[wid*5+3]=x1s; red[wid*5+4]=y0s;
  }
  __syncthreads();
  if (t < 5){
    float sum = 0.f;
    #pragma unroll
    for (int w = 0; w < 16; ++w) sum += red[w*5 + t];
    out[1 + b*5 + t] = sum;
  }
}

__global__ __launch_bounds__(512)
void qnn_loss(const int* __restrict__ y, float* __restrict__ out)
{
  __shared__ float red[8];
  int t = threadIdx.x;
  const float* o = out + 1 + t*5;
  float o0=o[0], o1=o[1], o2=o[2], o3=o[3], o4=o[4];
  float m = fmaxf(fmaxf(fmaxf(o0,o1), fmaxf(o2,o3)), o4);
  float sum = expf(o0-m)+expf(o1-m)+expf(o2-m)+expf(o3-m)+expf(o4-m);
  float lse = m + logf(sum);
  int yi = y[t]; yi = yi < 0 ? 0 : (yi > 4 ? 4 : yi);
  float lb = lse - o[yi];

  #pragma unroll
  for (int ofs = 32; ofs >= 1; ofs >>= 1) lb += __shfl_down(lb, ofs, 64);
  if ((t & 63) == 0) red[t >> 6] = lb;
  __syncthreads();
  if (t == 0){
    float s = 0.f;
    #pragma unroll
    for (int w = 0; w < 8; ++w) s += red[w];
    out[0] = s / (float)BATCH;
  }
}

extern "C" void kernel_launch(void* const* d_in, const int* in_sizes, int n_in,
                              void* d_out, int out_size, void* d_ws, size_t ws_size,
                              hipStream_t stream)
{
  const void* z     = d_in[0];
  const void* theta = d_in[1];
  const int*  y     = (const int*)d_in[2];
  float*      out   = (float*)d_out;

  qnn_circuit<<<BATCH, NT, 0, stream>>>(z, theta, out);
  qnn_loss<<<1, 512, 0, stream>>>(y, out);
}